// Round 1
// baseline (196.956 us; speedup 1.0000x reference)
//
#include <hip/hip_runtime.h>

#define BLOCK   512           // threads per block (8 waves)
#define NBLK    512           // grid: 2 blocks/CU, 16 waves/CU -> BW-saturating
#define NBINS   256           // global expert-id space
#define NWAVES  (BLOCK / 64)
#define UNROLL  4             // int4 loads per thread per grid-stride iter

// Fused kernel: per-wave privatized LDS histogram with INLINE affine-map
// detection, then a direct packed-u64 global-atomic flush into d_out
// (d_out pre-zeroed by a 256 B memset node on the same stream).
// No workspace, no second reduce dispatch.
//
// Atomic-tail budget: d_out is 64 dwords = 2 cache lines, so flush atomics
// serialize on ~2 L2 slices. We minimize ops: 512 blocks x 32 packed-u64
// atomics = 16K ops -> ~2-3 us worst-case, overlapped with block drain.
__global__ __launch_bounds__(BLOCK) void hist_fused(const int* __restrict__ ids,
                                                    int N,
                                                    const int* __restrict__ emap,
                                                    int emap_n,
                                                    int* __restrict__ out,
                                                    int n_local) {
    __shared__ int hist[NWAVES * NBINS];
    __shared__ int lmap[NBINS];
    __shared__ int fold[NBINS];
    __shared__ int s_lo, s_cnt, s_ok;
    const int tid = threadIdx.x;

    if (tid == 0) { s_lo = 0x7FFFFFFF; s_cnt = 0; s_ok = 1; }
    for (int i = tid; i < NWAVES * NBINS; i += BLOCK) hist[i] = 0;
    __syncthreads();

    // Pass 1: window min + count of valid entries; stash map in LDS.
    for (int g = tid; g < NBINS; g += BLOCK) {
        int m = (g < emap_n) ? emap[g] : -1;
        lmap[g] = m;
        if (m >= 0) { atomicMin(&s_lo, g); atomicAdd(&s_cnt, 1); }
    }
    __syncthreads();
    const int lo = s_lo;
    const unsigned cnt = (unsigned)s_cnt;
    // Pass 2: verify map is exactly the affine window g -> g - lo.
    for (int g = tid; g < NBINS; g += BLOCK) {
        int expect = (g >= lo && (unsigned)(g - lo) < cnt) ? (g - lo) : -1;
        if (lmap[g] != expect) s_ok = 0;   // benign race, all writers store 0
    }
    __syncthreads();
    const int affine = s_ok;

    int* h = &hist[(tid >> 6) * NBINS];

    const int4* __restrict__ ids4 = (const int4*)ids;
    const int n4      = N >> 2;
    const int chunk   = BLOCK * UNROLL;
    const int gstride = (int)gridDim.x * chunk;
    const int n4_full = (n4 / gstride) * gstride;

    if (affine) {
        for (int i = (int)blockIdx.x * chunk + tid; i < n4_full; i += gstride) {
            int4 v[UNROLL];
#pragma unroll
            for (int u = 0; u < UNROLL; ++u) v[u] = ids4[i + u * BLOCK];
#pragma unroll
            for (int u = 0; u < UNROLL; ++u) {
                unsigned a = (unsigned)(v[u].x - lo);
                unsigned b = (unsigned)(v[u].y - lo);
                unsigned c = (unsigned)(v[u].z - lo);
                unsigned d = (unsigned)(v[u].w - lo);
                if (a < cnt) atomicAdd(&h[a], 1);
                if (b < cnt) atomicAdd(&h[b], 1);
                if (c < cnt) atomicAdd(&h[c], 1);
                if (d < cnt) atomicAdd(&h[d], 1);
            }
        }
        for (int i = n4_full + (int)blockIdx.x * BLOCK + tid; i < n4;
             i += (int)gridDim.x * BLOCK) {
            int4 v = ids4[i];
            unsigned a = (unsigned)(v.x - lo), b = (unsigned)(v.y - lo);
            unsigned c = (unsigned)(v.z - lo), d = (unsigned)(v.w - lo);
            if (a < cnt) atomicAdd(&h[a], 1);
            if (b < cnt) atomicAdd(&h[b], 1);
            if (c < cnt) atomicAdd(&h[c], 1);
            if (d < cnt) atomicAdd(&h[d], 1);
        }
        if (blockIdx.x == 0) {
            for (int i = (n4 << 2) + tid; i < N; i += BLOCK) {
                unsigned a = (unsigned)(ids[i] - lo);
                if (a < cnt) atomicAdd(&h[a], 1);
            }
        }
    } else {
        for (int i = (int)blockIdx.x * chunk + tid; i < n4_full; i += gstride) {
            int4 v[UNROLL];
#pragma unroll
            for (int u = 0; u < UNROLL; ++u) v[u] = ids4[i + u * BLOCK];
#pragma unroll
            for (int u = 0; u < UNROLL; ++u) {
                int l0 = ((unsigned)v[u].x < NBINS) ? lmap[v[u].x] : -1;
                int l1 = ((unsigned)v[u].y < NBINS) ? lmap[v[u].y] : -1;
                int l2 = ((unsigned)v[u].z < NBINS) ? lmap[v[u].z] : -1;
                int l3 = ((unsigned)v[u].w < NBINS) ? lmap[v[u].w] : -1;
                if (l0 >= 0) atomicAdd(&h[l0], 1);
                if (l1 >= 0) atomicAdd(&h[l1], 1);
                if (l2 >= 0) atomicAdd(&h[l2], 1);
                if (l3 >= 0) atomicAdd(&h[l3], 1);
            }
        }
        for (int i = n4_full + (int)blockIdx.x * BLOCK + tid; i < n4;
             i += (int)gridDim.x * BLOCK) {
            int4 v = ids4[i];
            int l0 = ((unsigned)v.x < NBINS) ? lmap[v.x] : -1;
            int l1 = ((unsigned)v.y < NBINS) ? lmap[v.y] : -1;
            int l2 = ((unsigned)v.z < NBINS) ? lmap[v.z] : -1;
            int l3 = ((unsigned)v.w < NBINS) ? lmap[v.w] : -1;
            if (l0 >= 0) atomicAdd(&h[l0], 1);
            if (l1 >= 0) atomicAdd(&h[l1], 1);
            if (l2 >= 0) atomicAdd(&h[l2], 1);
            if (l3 >= 0) atomicAdd(&h[l3], 1);
        }
        if (blockIdx.x == 0) {
            for (int i = (n4 << 2) + tid; i < N; i += BLOCK) {
                int v = ids[i];
                int l = ((unsigned)v < NBINS) ? lmap[v] : -1;
                if (l >= 0) atomicAdd(&h[l], 1);
            }
        }
    }
    __syncthreads();

    // Fold wave copies into fold[] (stride NBINS*4 B between copies:
    // same-bank per thread but only 2-way lane aliasing -> free).
    for (int b = tid; b < n_local; b += BLOCK) {
        int s = 0;
#pragma unroll
        for (int w = 0; w < NWAVES; ++w) s += hist[w * NBINS + b];
        fold[b] = s;
    }
    __syncthreads();

    // Packed flush: 2 bins per u64 atomic (per-bin totals << 2^32, so no
    // carry crosses the 32-bit boundary). Little-endian: u64 at byte 8p
    // covers out[2p] (low) and out[2p+1] (high).
    const int npair = n_local >> 1;
    for (int p = tid; p < npair; p += BLOCK) {
        unsigned long long v =
            (unsigned long long)(unsigned)fold[2 * p] |
            ((unsigned long long)(unsigned)fold[2 * p + 1] << 32);
        if (v) atomicAdd((unsigned long long*)out + p, v);
    }
    if ((n_local & 1) && tid == 0) {
        int s = fold[n_local - 1];
        if (s) atomicAdd(&out[n_local - 1], s);
    }
}

extern "C" void kernel_launch(void* const* d_in, const int* in_sizes, int n_in,
                              void* d_out, int out_size, void* d_ws, size_t ws_size,
                              hipStream_t stream) {
    const int* topk_ids   = (const int*)d_in[0];
    // d_in[1] = num_local_experts (device scalar) == out_size; use out_size.
    const int* expert_map = (const int*)d_in[2];
    const int N       = in_sizes[0];
    const int emap_n  = in_sizes[2];
    const int n_local = out_size;

    // Zero the 256 B output (memset node in the captured graph), then one
    // fused kernel accumulates directly into it. No workspace use.
    hipMemsetAsync(d_out, 0, (size_t)n_local * sizeof(int), stream);
    hist_fused<<<NBLK, BLOCK, 0, stream>>>(topk_ids, N, expert_map, emap_n,
                                           (int*)d_out, n_local);
}